// Round 9
// baseline (166.416 us; speedup 1.0000x reference)
//
#include <hip/hip_runtime.h>
#include <math.h>
#include <float.h>

// ChamferLoss: set1/set2 [8, 4096, 3] fp32 -> scalar
// out = (sum of per-point min dists, both directions) / (8*4096*4096)
//
// v9 = v7 structure + VGPR-pinned inline-asm MFMA, rep=8 diagnostic.
// v8 decode: dur = 62.65us (harness-fixed) + R * k, k(v7) = 11.5us vs
// ~4.5us pipe floor. Surviving theory after 4 neutral structural rewrites:
// compiler places f32x16 accumulators in AGPRs -> every fold pays 16
// v_accvgpr_read per MFMA (invariant under restructuring). Fix: inline asm
// v_mfma_f32_32x32x16_f16 with "v" constraints (A,B,C,D all arch VGPRs;
// C-in = persistent zeroed z16). Hazards self-protected: s_nop 2 before
// (VALU-write -> MFMA-src-read), paired MFMAs + s_nop 7/7/1 after
// (MFMA-write -> VALU-read needs ~18 cy; 2nd MFMA's 16 issue cycles cover
// most of the 1st's). rep=8: blocks 0..1023 repeated 8x, atomic scale /8,
// output unchanged; dispatch ~8k us -> finally visible in top-5 counters.
// Decode next round: k' = (dur - 62.65)/8; revert to rep=1 with winner.
//
// Math (unchanged, HW-validated): d^2 = q2 + [p2 - 2 q.p] via one
// 32x32x16 f16 MFMA per 32x32 (point x query) tile, fp16 hi/lo split:
//   A lanes 0-31 (k0-7):  [phx,phy,phz, plx,ply,plz, p2h,p2l]
//   A lanes 32-63 (k8-15): same 16B masked to [phx,phy,phz, 0...]
//   B k0-7:  [-2qhx,-2qhy,-2qhz, -2qhx,-2qhy,-2qhz, 1, 1]
//   B k8-15: [-2qlx,-2qly,-2qlz, 0...]
// = p2h+p2l - 2qh.(ph+pl) - 2ql.ph  (drops ql.pl ~2^-24 rel).
// C/D: col=lane&31 = query; min over point-rows = reg folds + shfl_xor(32).

#define NPTS 4096

typedef __attribute__((ext_vector_type(8)))  _Float16 f16x8;
typedef __attribute__((ext_vector_type(16))) float    f32x16;

static __device__ __forceinline__ unsigned h2u(_Float16 h) {
    return (unsigned)__builtin_bit_cast(unsigned short, h);
}
static __device__ __forceinline__ unsigned pack2(unsigned a, unsigned b) {
    return (a & 0xFFFFu) | (b << 16);
}
static __device__ __forceinline__ uint4 packpt(float x, float y, float z) {
    const _Float16 hx = (_Float16)x, hy = (_Float16)y, hz = (_Float16)z;
    const _Float16 lx = (_Float16)(x - (float)hx);
    const _Float16 ly = (_Float16)(y - (float)hy);
    const _Float16 lz = (_Float16)(z - (float)hz);
    const float p2 = fmaf(x, x, fmaf(y, y, z * z));
    const _Float16 p2h = (_Float16)p2;
    const _Float16 p2l = (_Float16)(p2 - (float)p2h);
    return make_uint4(pack2(h2u(hx),  h2u(hy)),
                      pack2(h2u(hz),  h2u(lx)),
                      pack2(h2u(ly),  h2u(lz)),
                      pack2(h2u(p2h), h2u(p2l)));
}

__device__ __forceinline__ float fold16(const f32x16 c, float m) {
    // 8 x v_min3_f32: min over this column's 16 point-rows + running min
    m = fminf(fminf(c[0],  c[1]),  m);
    m = fminf(fminf(c[2],  c[3]),  m);
    m = fminf(fminf(c[4],  c[5]),  m);
    m = fminf(fminf(c[6],  c[7]),  m);
    m = fminf(fminf(c[8],  c[9]),  m);
    m = fminf(fminf(c[10], c[11]), m);
    m = fminf(fminf(c[12], c[13]), m);
    m = fminf(fminf(c[14], c[15]), m);
    return m;
}

__global__ __launch_bounds__(512, 4)
void chamfer_fused(const float* __restrict__ set1,
                   const float* __restrict__ set2,
                   float* __restrict__ out)
{
    __shared__ uint4 buf[2][1024];        // 32 KB; head of buf[0] reused as part[]

    const int blk = blockIdx.x & 1023;    // rep=8: higher bits repeat the work
    const int dir = blk >> 9;             // 0: q=set1 db=set2, 1: swapped
    const int rem = blk & 511;
    const int b   = rem >> 6;             // batch 0..7
    const int qc  = rem & 63;             // 64-query chunk 0..63

    const float* __restrict__ Q  = (dir ? set2 : set1) + (size_t)b * NPTS * 3;
    const float* __restrict__ DB = (dir ? set1 : set2) + (size_t)b * NPTS * 3;

    const int t    = threadIdx.x;
    const int lane = t & 63;
    const int w    = t >> 6;              // wave 0..7
    const int col  = lane & 31;
    const int half = lane >> 5;           // 0: k0-7, 1: k8-15
    const int qbase = qc * 64;

    // ---- B-frags: 2 query tiles, built per-lane from raw floats ----
    f16x8 Bf0, Bf1;
    #pragma unroll
    for (int j = 0; j < 2; ++j) {
        const float* qp = Q + (size_t)(qbase + j * 32 + col) * 3;
        const float qx = qp[0], qy = qp[1], qz = qp[2];
        const _Float16 hx = (_Float16)qx, hy = (_Float16)qy, hz = (_Float16)qz;
        uint4 bv;
        if (!half) {
            const unsigned mx = h2u((_Float16)(-2.0f * (float)hx));
            const unsigned my = h2u((_Float16)(-2.0f * (float)hy));
            const unsigned mz = h2u((_Float16)(-2.0f * (float)hz));
            const unsigned one = 0x3C00u;               // fp16 1.0
            bv = make_uint4(pack2(mx, my), pack2(mz, mx),
                            pack2(my, mz), pack2(one, one));
        } else {
            const unsigned mx = h2u((_Float16)(-2.0f * (qx - (float)hx)));
            const unsigned my = h2u((_Float16)(-2.0f * (qy - (float)hy)));
            const unsigned mz = h2u((_Float16)(-2.0f * (qz - (float)hz)));
            bv = make_uint4(pack2(mx, my), pack2(mz, 0), 0u, 0u);
        }
        if (j == 0) Bf0 = __builtin_bit_cast(f16x8, bv);
        else        Bf1 = __builtin_bit_cast(f16x8, bv);
    }

    // ---- stage half 0 (1024 points, 2 per thread) ----
    {
        const float* s = DB + 3 * t;
        buf[0][t]       = packpt(s[0], s[1], s[2]);
        const float* s2 = DB + 3 * (t + 512);
        buf[0][t + 512] = packpt(s2[0], s2[1], s2[2]);
    }
    __syncthreads();

    const unsigned mY  = half ? 0x0000FFFFu : 0xFFFFFFFFu;  // keep phz, drop plx
    const unsigned mZW = half ? 0u          : 0xFFFFFFFFu;  // drop ply..p2l
    const f32x16 z16 = {0,0,0,0,0,0,0,0,0,0,0,0,0,0,0,0};   // persistent C-in
    float dm0 = FLT_MAX, dm1 = FLT_MAX;

    // ---- 4 phases: compute buf[h] (4 tiles/wave) || stage buf[h+1] ----
    for (int h = 0; h < 4; ++h) {
        const uint4* __restrict__ fb = &buf[h & 1][w * 128 + col];
        const uint4 u0 = fb[0];
        const uint4 u1 = fb[32];
        const uint4 u2 = fb[64];
        const uint4 u3 = fb[96];

        // issue next-half global loads early (latency hides under MFMA)
        float sx0 = 0, sy0 = 0, sz0 = 0, sx1 = 0, sy1 = 0, sz1 = 0;
        if (h < 3) {
            const float* s = DB + 3 * ((h + 1) * 1024 + t);
            sx0 = s[0]; sy0 = s[1]; sz0 = s[2];
            const float* s2 = s + 3 * 512;
            sx1 = s2[0]; sy1 = s2[1]; sz1 = s2[2];
        }

        // VGPR-pinned MFMA pair: D,A,B,C all arch VGPRs ("v"), no AGPR
        // round-trip. s_nop 2: VALU-write->MFMA-src hazard. Tail: c0 gets
        // 16cy (2nd MFMA) + 18cy nops; c1 gets 18cy before any VALU read.
        #define TILE(U) do {                                                   \
            const uint4 am = make_uint4((U).x, (U).y & mY,                     \
                                        (U).z & mZW, (U).w & mZW);             \
            const f16x8 av = __builtin_bit_cast(f16x8, am);                    \
            f32x16 c0, c1;                                                     \
            asm("s_nop 2\n\t"                                                  \
                "v_mfma_f32_32x32x16_f16 %0, %2, %3, %5\n\t"                   \
                "v_mfma_f32_32x32x16_f16 %1, %2, %4, %5\n\t"                   \
                "s_nop 7\n\t"                                                  \
                "s_nop 7\n\t"                                                  \
                "s_nop 1"                                                      \
                : "=&v"(c0), "=&v"(c1)                                         \
                : "v"(av), "v"(Bf0), "v"(Bf1), "v"(z16));                      \
            dm0 = fold16(c0, dm0);                                             \
            dm1 = fold16(c1, dm1);                                             \
        } while (0)

        TILE(u0); TILE(u1); TILE(u2); TILE(u3);
        #undef TILE

        // pack + write next half (write-late; drains at the barrier)
        if (h < 3) {
            buf[(h + 1) & 1][t]       = packpt(sx0, sy0, sz0);
            buf[(h + 1) & 1][t + 512] = packpt(sx1, sy1, sz1);
        }
        __syncthreads();
    }

    // ---- combine row-halves; reuse buf LDS as part[8][64] ----
    const float v0 = fminf(dm0, __shfl_xor(dm0, 32));
    const float v1 = fminf(dm1, __shfl_xor(dm1, 32));
    float* part = (float*)&buf[0][0];     // 2 KB of the 32 KB buffer
    if (!half) {
        part[w * 64 + col]      = v0;
        part[w * 64 + 32 + col] = v1;
    }
    __syncthreads();

    // ---- final: min over 8 waves, add q2 (fp32 exact), sqrt, sum ----
    float dist = 0.0f;
    if (t < 64) {
        float m = part[t];
        #pragma unroll
        for (int ww = 1; ww < 8; ++ww)
            m = fminf(m, part[ww * 64 + t]);
        const float* qp = Q + (size_t)(qbase + t) * 3;
        const float q2 = fmaf(qp[0], qp[0], fmaf(qp[1], qp[1], qp[2] * qp[2]));
        dist = sqrtf(fmaxf(q2 + m, 0.0f));
    }
    #pragma unroll
    for (int off = 32; off > 0; off >>= 1)
        dist += __shfl_down(dist, off);
    if (t == 0)
        atomicAdd(out, dist * (1.0f / 1073741824.0f));  // 1/(8 * 8*4096*4096)
}

extern "C" void kernel_launch(void* const* d_in, const int* in_sizes, int n_in,
                              void* d_out, int out_size, void* d_ws, size_t ws_size,
                              hipStream_t stream) {
    const float* s1 = (const float*)d_in[0];
    const float* s2 = (const float*)d_in[1];
    float* out = (float*)d_out;

    hipMemsetAsync(out, 0, sizeof(float), stream);  // d_out poisoned 0xAA each call
    chamfer_fused<<<dim3(8192), dim3(512), 0, stream>>>(s1, s2, out);
}

// Round 10
// 73.824 us; speedup vs baseline: 2.2542x; 2.2542x over previous
//
#include <hip/hip_runtime.h>
#include <math.h>
#include <float.h>

// ChamferLoss: set1/set2 [8, 4096, 3] fp32 -> scalar
// out = (sum of per-point min dists, both directions) / (8*4096*4096)
//
// v10 = v7 structure, intrinsic MFMA, NO per-tile masks, rep=1.
// v9 rep=8 diagnostic (first visible counters): VALUBusy 64% >> MfmaUtil 24%,
// VGPR=40, conflicts 0. MfmaUtil*dur = 3.4us/pass = exact MFMA-pipe floor ->
// kernel is VALU-bound + ~35% stalls. Fixes:
//  - masks removed: B's k11-15 are ZERO, so A junk in those slots multiplies
//    to nothing -- the v6 masks (3 v_and + operand rebuild per tile) were
//    redundant and forced a VALU-write->MFMA-src dep before every MFMA.
//    Now ds_read_b128 feeds the MFMA operand directly.
//  - intrinsics, not asm: compiler schedules folds under MFMA latency and
//    inserts minimal hazard nops (v9's s_nop walls cost ~2.9us/pass).
// Per-pass model: MFMA 3.4us, VALU ~3.2us (fold 8 v_min3/MFMA = 1.7 +
// staging 1.1 + misc) -> balanced, target k ~= 5.5-7us.
//
// Math (HW-validated v4-v9): d^2 = q2 + [p2 - 2 q.p] via one
// v_mfma_f32_32x32x16_f16 per 32x32 (point x query) tile, fp16 hi/lo split:
//   A (all 64 lanes, same 16B): [phx,phy,phz, plx,ply,plz, p2h,p2l]
//   B k0-7:  [-2qhx,-2qhy,-2qhz, -2qhx,-2qhy,-2qhz, 1, 1]
//   B k8-15: [-2qlx,-2qly,-2qlz, 0,0,0,0,0]   (zeros kill A k11-15 junk)
// = p2h+p2l - 2qh.(ph+pl) - 2ql.ph  (drops ql.pl ~2^-24 rel).
// C/D: col=lane&31 = query; min over point-rows = reg folds + shfl_xor(32).

#define NPTS 4096

typedef __attribute__((ext_vector_type(8)))  _Float16 f16x8;
typedef __attribute__((ext_vector_type(16))) float    f32x16;

static __device__ __forceinline__ unsigned h2u(_Float16 h) {
    return (unsigned)__builtin_bit_cast(unsigned short, h);
}
static __device__ __forceinline__ unsigned pack2(unsigned a, unsigned b) {
    return (a & 0xFFFFu) | (b << 16);
}
static __device__ __forceinline__ uint4 packpt(float x, float y, float z) {
    const _Float16 hx = (_Float16)x, hy = (_Float16)y, hz = (_Float16)z;
    const _Float16 lx = (_Float16)(x - (float)hx);
    const _Float16 ly = (_Float16)(y - (float)hy);
    const _Float16 lz = (_Float16)(z - (float)hz);
    const float p2 = fmaf(x, x, fmaf(y, y, z * z));
    const _Float16 p2h = (_Float16)p2;
    const _Float16 p2l = (_Float16)(p2 - (float)p2h);
    return make_uint4(pack2(h2u(hx),  h2u(hy)),
                      pack2(h2u(hz),  h2u(lx)),
                      pack2(h2u(ly),  h2u(lz)),
                      pack2(h2u(p2h), h2u(p2l)));
}

__device__ __forceinline__ float fold16(const f32x16 c, float m) {
    // 8 x v_min3_f32: min over this column's 16 point-rows + running min
    m = fminf(fminf(c[0],  c[1]),  m);
    m = fminf(fminf(c[2],  c[3]),  m);
    m = fminf(fminf(c[4],  c[5]),  m);
    m = fminf(fminf(c[6],  c[7]),  m);
    m = fminf(fminf(c[8],  c[9]),  m);
    m = fminf(fminf(c[10], c[11]), m);
    m = fminf(fminf(c[12], c[13]), m);
    m = fminf(fminf(c[14], c[15]), m);
    return m;
}

__global__ __launch_bounds__(512, 4)
void chamfer_fused(const float* __restrict__ set1,
                   const float* __restrict__ set2,
                   float* __restrict__ out)
{
    __shared__ uint4 buf[2][1024];        // 32 KB; head of buf[0] reused as part[]

    const int blk = blockIdx.x;           // 0..1023
    const int dir = blk >> 9;             // 0: q=set1 db=set2, 1: swapped
    const int rem = blk & 511;
    const int b   = rem >> 6;             // batch 0..7
    const int qc  = rem & 63;             // 64-query chunk 0..63

    const float* __restrict__ Q  = (dir ? set2 : set1) + (size_t)b * NPTS * 3;
    const float* __restrict__ DB = (dir ? set1 : set2) + (size_t)b * NPTS * 3;

    const int t    = threadIdx.x;
    const int lane = t & 63;
    const int w    = t >> 6;              // wave 0..7
    const int col  = lane & 31;
    const int half = lane >> 5;           // 0: B supplies k0-7, 1: k8-15
    const int qbase = qc * 64;

    // ---- B-frags: 2 query tiles, built per-lane from raw floats ----
    f16x8 Bf0, Bf1;
    #pragma unroll
    for (int j = 0; j < 2; ++j) {
        const float* qp = Q + (size_t)(qbase + j * 32 + col) * 3;
        const float qx = qp[0], qy = qp[1], qz = qp[2];
        const _Float16 hx = (_Float16)qx, hy = (_Float16)qy, hz = (_Float16)qz;
        uint4 bv;
        if (!half) {
            const unsigned mx = h2u((_Float16)(-2.0f * (float)hx));
            const unsigned my = h2u((_Float16)(-2.0f * (float)hy));
            const unsigned mz = h2u((_Float16)(-2.0f * (float)hz));
            const unsigned one = 0x3C00u;               // fp16 1.0
            bv = make_uint4(pack2(mx, my), pack2(mz, mx),
                            pack2(my, mz), pack2(one, one));
        } else {
            const unsigned mx = h2u((_Float16)(-2.0f * (qx - (float)hx)));
            const unsigned my = h2u((_Float16)(-2.0f * (qy - (float)hy)));
            const unsigned mz = h2u((_Float16)(-2.0f * (qz - (float)hz)));
            bv = make_uint4(pack2(mx, my), pack2(mz, 0), 0u, 0u);
        }
        if (j == 0) Bf0 = __builtin_bit_cast(f16x8, bv);
        else        Bf1 = __builtin_bit_cast(f16x8, bv);
    }

    // ---- stage half 0 (1024 points, 2 per thread) ----
    {
        const float* s = DB + 3 * t;
        buf[0][t]       = packpt(s[0], s[1], s[2]);
        const float* s2 = DB + 3 * (t + 512);
        buf[0][t + 512] = packpt(s2[0], s2[1], s2[2]);
    }
    __syncthreads();

    const f32x16 z16 = {0,0,0,0,0,0,0,0,0,0,0,0,0,0,0,0};
    float dm0 = FLT_MAX, dm1 = FLT_MAX;

    // ---- 4 phases: compute buf[h] (4 tiles/wave) || stage buf[h+1] ----
    for (int h = 0; h < 4; ++h) {
        // A-frags: ds_read_b128 results feed MFMA directly (no VALU rebuild)
        const f16x8* __restrict__ fb =
            (const f16x8*)&buf[h & 1][w * 128 + col];
        const f16x8 a0 = fb[0];
        const f16x8 a1 = fb[32];
        const f16x8 a2 = fb[64];
        const f16x8 a3 = fb[96];

        // issue next-half global loads early (latency hides under MFMA)
        float sx0 = 0, sy0 = 0, sz0 = 0, sx1 = 0, sy1 = 0, sz1 = 0;
        if (h < 3) {
            const float* s = DB + 3 * ((h + 1) * 1024 + t);
            sx0 = s[0]; sy0 = s[1]; sz0 = s[2];
            const float* s2 = s + 3 * 512;
            sx1 = s2[0]; sy1 = s2[1]; sz1 = s2[2];
        }

        f32x16 c;
        c = __builtin_amdgcn_mfma_f32_32x32x16_f16(a0, Bf0, z16, 0, 0, 0);
        dm0 = fold16(c, dm0);
        c = __builtin_amdgcn_mfma_f32_32x32x16_f16(a0, Bf1, z16, 0, 0, 0);
        dm1 = fold16(c, dm1);
        c = __builtin_amdgcn_mfma_f32_32x32x16_f16(a1, Bf0, z16, 0, 0, 0);
        dm0 = fold16(c, dm0);
        c = __builtin_amdgcn_mfma_f32_32x32x16_f16(a1, Bf1, z16, 0, 0, 0);
        dm1 = fold16(c, dm1);
        c = __builtin_amdgcn_mfma_f32_32x32x16_f16(a2, Bf0, z16, 0, 0, 0);
        dm0 = fold16(c, dm0);
        c = __builtin_amdgcn_mfma_f32_32x32x16_f16(a2, Bf1, z16, 0, 0, 0);
        dm1 = fold16(c, dm1);
        c = __builtin_amdgcn_mfma_f32_32x32x16_f16(a3, Bf0, z16, 0, 0, 0);
        dm0 = fold16(c, dm0);
        c = __builtin_amdgcn_mfma_f32_32x32x16_f16(a3, Bf1, z16, 0, 0, 0);
        dm1 = fold16(c, dm1);

        // pack + write next half (write-late; drains at the barrier)
        if (h < 3) {
            buf[(h + 1) & 1][t]       = packpt(sx0, sy0, sz0);
            buf[(h + 1) & 1][t + 512] = packpt(sx1, sy1, sz1);
        }
        __syncthreads();
    }

    // ---- combine row-halves; reuse buf LDS as part[8][64] ----
    const float v0 = fminf(dm0, __shfl_xor(dm0, 32));
    const float v1 = fminf(dm1, __shfl_xor(dm1, 32));
    float* part = (float*)&buf[0][0];     // 2 KB of the 32 KB buffer
    if (!half) {
        part[w * 64 + col]      = v0;
        part[w * 64 + 32 + col] = v1;
    }
    __syncthreads();

    // ---- final: min over 8 waves, add q2 (fp32 exact), sqrt, sum ----
    float dist = 0.0f;
    if (t < 64) {
        float m = part[t];
        #pragma unroll
        for (int ww = 1; ww < 8; ++ww)
            m = fminf(m, part[ww * 64 + t]);
        const float* qp = Q + (size_t)(qbase + t) * 3;
        const float q2 = fmaf(qp[0], qp[0], fmaf(qp[1], qp[1], qp[2] * qp[2]));
        dist = sqrtf(fmaxf(q2 + m, 0.0f));
    }
    #pragma unroll
    for (int off = 32; off > 0; off >>= 1)
        dist += __shfl_down(dist, off);
    if (t == 0)
        atomicAdd(out, dist * (1.0f / 134217728.0f));   // 1/(8*4096*4096)
}

extern "C" void kernel_launch(void* const* d_in, const int* in_sizes, int n_in,
                              void* d_out, int out_size, void* d_ws, size_t ws_size,
                              hipStream_t stream) {
    const float* s1 = (const float*)d_in[0];
    const float* s2 = (const float*)d_in[1];
    float* out = (float*)d_out;

    hipMemsetAsync(out, 0, sizeof(float), stream);  // d_out poisoned 0xAA each call
    chamfer_fused<<<dim3(1024), dim3(512), 0, stream>>>(s1, s2, out);
}